// Round 3
// baseline (513.427 us; speedup 1.0000x reference)
//
#include <hip/hip_runtime.h>

#define N_SEQ 16384
#define T 16
#define E 30
#define H 50
#define G4 200   // 4*H
#define NS 8     // sequences per block
#define VOCAB 100

typedef float float2v __attribute__((ext_vector_type(2)));

// tbl[v][g] = dot(emb[v], w_ih[g]) + b_ih[g] + b_hh[g]
__global__ void build_tbl(const float* __restrict__ emb,
                          const float* __restrict__ w_ih,
                          const float* __restrict__ b_ih,
                          const float* __restrict__ b_hh,
                          float* __restrict__ tbl) {
    int idx = blockIdx.x * blockDim.x + threadIdx.x;
    if (idx >= VOCAB * G4) return;
    int v = idx / G4, g = idx % G4;
    float s = b_ih[g] + b_hh[g];
    const float* er = emb + v * E;
    const float* wr = w_ih + g * E;
#pragma unroll
    for (int e = 0; e < E; ++e) s += er[e] * wr[e];
    tbl[idx] = s;
}

__device__ __forceinline__ float sigm(float x) { return 1.0f / (1.0f + __expf(-x)); }
__device__ __forceinline__ float ftanh(float x) {
    float e = __expf(2.0f * x);
    return (e - 1.0f) / (e + 1.0f);
}

__global__ __launch_bounds__(256, 1) void lstm_kernel(
    const int* __restrict__ ids,     // [N_SEQ, T]
    const float* __restrict__ tbl,   // [2][VOCAB][G4]  (fwd then rev)
    const float* __restrict__ whh_f, // [G4][H]
    const float* __restrict__ whh_r, // [G4][H]
    float* __restrict__ out)         // [N_SEQ, 2*H]
{
    __shared__ __align__(16) float s_h[NS][52];   // h state, padded stride
    __shared__ float s_g[NS][G4];                 // gate pre-activations
    __shared__ int s_ids[NS][T];
    __shared__ int s_capt[NS];

    const int tid = threadIdx.x;
    const int nb = N_SEQ / NS; // 2048 blocks per direction
    const int b = blockIdx.x;
    const int dir = (b >= nb) ? 1 : 0;
    const int s0 = (dir ? (b - nb) : b) * NS;

    const float* __restrict__ whh = dir ? whh_r : whh_f;
    const float* __restrict__ tb  = tbl + dir * (VOCAB * G4);

    // load ids for this block's sequences
    if (tid < NS * T) {
        int s = tid / T, t = tid % T;
        s_ids[s][t] = ids[(s0 + s) * T + t];
    }

    // R=2: thread (tid<100) owns gate rows row0=tid and row1=tid+100.
    // Load unconditionally with clamped row so liveness is branch-free.
    const int row0 = (tid < 100) ? tid : 99;
    const int row1 = row0 + 100;
    float2v w0[26], w1[26];
#pragma unroll
    for (int p = 0; p < 26; ++p) {
        int k0 = 2 * p, k1 = 2 * p + 1;
        float2v a, c;
        a[0] = (k0 < H) ? whh[row0 * H + k0] : 0.f;
        a[1] = (k1 < H) ? whh[row0 * H + k1] : 0.f;
        c[0] = (k0 < H) ? whh[row1 * H + k0] : 0.f;
        c[1] = (k1 < H) ? whh[row1 * H + k1] : 0.f;
        w0[p] = a; w1[p] = c;
    }
    // Pin the weight pairs into architectural VGPRs: asm outputs cannot be
    // rematerialized, so the allocator must keep all 104 VGPRs live.
    asm volatile("" : "+v"(w0[0]), "+v"(w0[1]), "+v"(w0[2]), "+v"(w0[3]),
                      "+v"(w0[4]), "+v"(w0[5]), "+v"(w0[6]), "+v"(w0[7]),
                      "+v"(w0[8]), "+v"(w0[9]), "+v"(w0[10]), "+v"(w0[11]),
                      "+v"(w0[12]));
    asm volatile("" : "+v"(w0[13]), "+v"(w0[14]), "+v"(w0[15]), "+v"(w0[16]),
                      "+v"(w0[17]), "+v"(w0[18]), "+v"(w0[19]), "+v"(w0[20]),
                      "+v"(w0[21]), "+v"(w0[22]), "+v"(w0[23]), "+v"(w0[24]),
                      "+v"(w0[25]));
    asm volatile("" : "+v"(w1[0]), "+v"(w1[1]), "+v"(w1[2]), "+v"(w1[3]),
                      "+v"(w1[4]), "+v"(w1[5]), "+v"(w1[6]), "+v"(w1[7]),
                      "+v"(w1[8]), "+v"(w1[9]), "+v"(w1[10]), "+v"(w1[11]),
                      "+v"(w1[12]));
    asm volatile("" : "+v"(w1[13]), "+v"(w1[14]), "+v"(w1[15]), "+v"(w1[16]),
                      "+v"(w1[17]), "+v"(w1[18]), "+v"(w1[19]), "+v"(w1[20]),
                      "+v"(w1[21]), "+v"(w1[22]), "+v"(w1[23]), "+v"(w1[24]),
                      "+v"(w1[25]));

    // init h = 0
    for (int i = tid; i < NS * 52; i += 256) ((float*)s_h)[i] = 0.f;
    __syncthreads();
    // ragged lengths -> forward capture step
    if (tid < NS) {
        int len = 0;
#pragma unroll
        for (int t = 0; t < T; ++t) len += (s_ids[tid][t] != 0) ? 1 : 0;
        s_capt[tid] = (len > 1) ? (len - 1) : 0;
    }

    // phase-2 ownership: tasks u = s*H + j, u in [0, NS*H=400)
    const int u1 = tid + 256;    // valid if tid < 144
    const int sa = tid / H, ja = tid % H;
    const int sb = u1 / H, jb = u1 % H;
    float c0 = 0.f, c1 = 0.f;

    for (int t = 0; t < T; ++t) {
        __syncthreads(); // s_h (and s_capt at t=0) ready
        const int tt = dir ? (T - 1 - t) : t;

        // ---- phase 1: gates[s][g] = tbl[id][g] + dot(h[s], w_hh[g]) ----
        if (tid < 100) {
            // issue table gathers first (latency overlaps the FMA chain)
            float g0[NS], g1[NS];
#pragma unroll
            for (int s = 0; s < NS; ++s) {
                int id = s_ids[s][tt];
                g0[s] = tb[id * G4 + tid];
                g1[s] = tb[id * G4 + tid + 100];
            }
            float2v a0[NS], a1[NS];
#pragma unroll
            for (int s = 0; s < NS; ++s) { a0[s] = (float2v)(0.f); a1[s] = (float2v)(0.f); }
#pragma unroll
            for (int k = 0; k < 13; ++k) {
#pragma unroll
                for (int s = 0; s < NS; ++s) {
                    float4 hv = *(const float4*)&s_h[s][k * 4]; // broadcast read
                    float2v hlo, hhi;
                    hlo[0] = hv.x; hlo[1] = hv.y;
                    hhi[0] = hv.z; hhi[1] = hv.w;
                    a0[s] = __builtin_elementwise_fma(hlo, w0[2 * k],     a0[s]);
                    a0[s] = __builtin_elementwise_fma(hhi, w0[2 * k + 1], a0[s]);
                    a1[s] = __builtin_elementwise_fma(hlo, w1[2 * k],     a1[s]);
                    a1[s] = __builtin_elementwise_fma(hhi, w1[2 * k + 1], a1[s]);
                }
            }
#pragma unroll
            for (int s = 0; s < NS; ++s) {
                s_g[s][tid]       = g0[s] + a0[s][0] + a0[s][1];
                s_g[s][tid + 100] = g1[s] + a1[s][0] + a1[s][1];
            }
        }
        __syncthreads();

        // ---- phase 2: per hidden unit c/h update ----
        {
            float gi = s_g[sa][ja], gf = s_g[sa][ja + H];
            float gg = s_g[sa][ja + 2 * H], go = s_g[sa][ja + 3 * H];
            float i_ = sigm(gi), f_ = sigm(gf), g_ = ftanh(gg), o_ = sigm(go);
            c0 = f_ * c0 + i_ * g_;
            float h = o_ * ftanh(c0);
            s_h[sa][ja] = h;
            if (dir == 0) {
                if (t == s_capt[sa]) out[(s0 + sa) * (2 * H) + ja] = h;
            } else {
                if (t == T - 1)      out[(s0 + sa) * (2 * H) + H + ja] = h;
            }
        }
        if (u1 < NS * H) {
            float gi = s_g[sb][jb], gf = s_g[sb][jb + H];
            float gg = s_g[sb][jb + 2 * H], go = s_g[sb][jb + 3 * H];
            float i_ = sigm(gi), f_ = sigm(gf), g_ = ftanh(gg), o_ = sigm(go);
            c1 = f_ * c1 + i_ * g_;
            float h = o_ * ftanh(c1);
            s_h[sb][jb] = h;
            if (dir == 0) {
                if (t == s_capt[sb]) out[(s0 + sb) * (2 * H) + jb] = h;
            } else {
                if (t == T - 1)      out[(s0 + sb) * (2 * H) + H + jb] = h;
            }
        }
    }
}

extern "C" void kernel_launch(void* const* d_in, const int* in_sizes, int n_in,
                              void* d_out, int out_size, void* d_ws, size_t ws_size,
                              hipStream_t stream) {
    const int*   char_ids = (const int*)d_in[0];
    const float* emb      = (const float*)d_in[1];
    const float* w_ih_f   = (const float*)d_in[2];
    const float* w_hh_f   = (const float*)d_in[3];
    const float* b_ih_f   = (const float*)d_in[4];
    const float* b_hh_f   = (const float*)d_in[5];
    const float* w_ih_r   = (const float*)d_in[6];
    const float* w_hh_r   = (const float*)d_in[7];
    const float* b_ih_r   = (const float*)d_in[8];
    const float* b_hh_r   = (const float*)d_in[9];
    float* out = (float*)d_out;
    float* tbl = (float*)d_ws; // [2][VOCAB][G4] = 160 KB

    const int nt = VOCAB * G4; // 20000
    build_tbl<<<(nt + 255) / 256, 256, 0, stream>>>(emb, w_ih_f, b_ih_f, b_hh_f, tbl);
    build_tbl<<<(nt + 255) / 256, 256, 0, stream>>>(emb, w_ih_r, b_ih_r, b_hh_r, tbl + nt);
    lstm_kernel<<<2 * (N_SEQ / NS), 256, 0, stream>>>(char_ids, tbl, w_hh_f, w_hh_r, out);
}

// Round 4
// 481.696 us; speedup vs baseline: 1.0659x; 1.0659x over previous
//
#include <hip/hip_runtime.h>

#define T 16
#define E 30
#define H 50
#define G4 200   // 4*H
#define VOCAB 100
#define NSEQ 16384

// tbl[v][g] = dot(emb[v], w_ih[g]) + b_ih[g] + b_hh[g]
__global__ void build_tbl(const float* __restrict__ emb,
                          const float* __restrict__ w_ih,
                          const float* __restrict__ b_ih,
                          const float* __restrict__ b_hh,
                          float* __restrict__ tbl) {
    int idx = blockIdx.x * blockDim.x + threadIdx.x;
    if (idx >= VOCAB * G4) return;
    int v = idx / G4, g = idx % G4;
    float s = b_ih[g] + b_hh[g];
    const float* er = emb + v * E;
    const float* wr = w_ih + g * E;
#pragma unroll
    for (int e = 0; e < E; ++e) s += er[e] * wr[e];
    tbl[idx] = s;
}

__device__ __forceinline__ float sigm(float x) { return 1.0f / (1.0f + __expf(-x)); }
__device__ __forceinline__ float ftanh(float x) {
    float e = __expf(2.0f * x);
    return (e - 1.0f) / (e + 1.0f);
}

// Thread = (sequence, k-half). Lane pair (2s,2s+1) owns sequence s.
// Lane parity p owns h/c for k in [25p, 25p+25). Per unit-pair iteration:
// 8 gate-row partial dots over the lane's k-half (200 FMA), one shfl_xor
// combine, activations, private h/c update. No barriers in the t-loop.
__global__ __launch_bounds__(256, 1) void lstm_kernel(
    const int* __restrict__ ids,     // [NSEQ, T]
    const float* __restrict__ tbl,   // [2][VOCAB][G4]
    const float* __restrict__ whh_f, // [G4][H]
    const float* __restrict__ whh_r, // [G4][H]
    float* __restrict__ out)         // [NSEQ, 2*H]
{
    // w layout: [row][56] with k<25 at slots 0..24, k>=25 at slots 28..52.
    // Even lanes read bytes [0,100), odd [112,212) of each row: two distinct
    // 16B-aligned broadcast groups per ds_read -> conflict-free.
    __shared__ __align__(16) float w_lds[G4 * 56];     // 44.8 KB
    __shared__ float h_lds[256 * 25];                  // 25.6 KB (stride 25: 2-way banks)
    __shared__ float c_lds[256 * 25];                  // 25.6 KB

    const int tid = threadIdx.x;
    const int b = blockIdx.x;
    const int dir = b >> 7;            // blocks 0-127 fwd, 128-255 rev
    const int pair = tid >> 1;
    const int p = tid & 1;
    const int seq = (b & 127) * 128 + pair;

    const float* __restrict__ whh = dir ? whh_r : whh_f;
    const float* __restrict__ tb  = tbl + dir * (VOCAB * G4);

    // stage w_hh into LDS with the holes layout
    for (int i = tid; i < G4 * H; i += 256) {
        int row = i / H, k = i - row * H;
        int slot = k + (k >= 25 ? 3 : 0);
        w_lds[row * 56 + slot] = whh[i];
    }
    // init private h/c
    float* myh = h_lds + tid * 25;
    float* myc = c_lds + tid * 25;
#pragma unroll
    for (int i = 0; i < 25; ++i) { myh[i] = 0.f; myc[i] = 0.f; }

    // ragged length -> forward capture step
    const int* __restrict__ myids = ids + seq * T;
    int len = 0;
    {
        const int4* q = (const int4*)myids;
        int4 a0 = q[0], a1 = q[1], a2 = q[2], a3 = q[3];
        len  = (a0.x != 0) + (a0.y != 0) + (a0.z != 0) + (a0.w != 0);
        len += (a1.x != 0) + (a1.y != 0) + (a1.z != 0) + (a1.w != 0);
        len += (a2.x != 0) + (a2.y != 0) + (a2.z != 0) + (a2.w != 0);
        len += (a3.x != 0) + (a3.y != 0) + (a3.z != 0) + (a3.w != 0);
    }
    const int capt = dir ? (T - 1) : ((len > 1) ? (len - 1) : 0);

    __syncthreads();   // w_lds ready (h/c are lane-private)

    for (int t = 0; t < T; ++t) {
        const int tt = dir ? (T - 1 - t) : t;
        const int id = myids[tt];
        const float* __restrict__ trow = tb + id * G4;

        // reload previous-step h into registers (old copy; writes below go to LDS)
        float hh[25];
#pragma unroll
        for (int k = 0; k < 25; ++k) hh[k] = myh[k];

#pragma unroll 2
        for (int idx = 0; idx < 25; ++idx) {
            const int unit = idx + 25 * p;   // this lane's unit for this slot
            // prefetch: consumed only after the FMA block (latency hidden)
            float tv0 = trow[unit];
            float tv1 = trow[unit + 50];
            float tv2 = trow[unit + 100];
            float tv3 = trow[unit + 150];
            float c_old = myc[idx];

            float acc[8];
#pragma unroll
            for (int m = 0; m < 8; ++m) acc[m] = 0.f;

            // rows: m<4 -> unit_even rows idx+50m ; m>=4 -> unit_odd rows idx+25+50(m-4)
#pragma unroll
            for (int m = 0; m < 8; ++m) {
                const int row = idx + ((m >= 4) ? 25 : 0) + 50 * (m & 3);
                const float* wr = w_lds + row * 56 + 28 * p;
#pragma unroll
                for (int i = 0; i < 6; ++i) {
                    float4 wv = *(const float4*)(wr + 4 * i);
                    acc[m] = fmaf(wv.x, hh[4 * i + 0], acc[m]);
                    acc[m] = fmaf(wv.y, hh[4 * i + 1], acc[m]);
                    acc[m] = fmaf(wv.z, hh[4 * i + 2], acc[m]);
                    acc[m] = fmaf(wv.w, hh[4 * i + 3], acc[m]);
                }
                acc[m] = fmaf(wr[24], hh[24], acc[m]);
            }
            // combine k-halves across the lane pair
#pragma unroll
            for (int m = 0; m < 8; ++m) acc[m] += __shfl_xor(acc[m], 1);

            // pick my unit's gates, add the input table term exactly once
            float g0 = (p ? acc[4] : acc[0]) + tv0;
            float g1 = (p ? acc[5] : acc[1]) + tv1;
            float g2 = (p ? acc[6] : acc[2]) + tv2;
            float g3 = (p ? acc[7] : acc[3]) + tv3;

            float i_ = sigm(g0), f_ = sigm(g1), gg = ftanh(g2), o_ = sigm(g3);
            float cn = fmaf(f_, c_old, i_ * gg);
            myc[idx] = cn;
            float hn = o_ * ftanh(cn);
            myh[idx] = hn;

            if (t == capt) out[seq * (2 * H) + dir * H + unit] = hn;
        }
    }
}

extern "C" void kernel_launch(void* const* d_in, const int* in_sizes, int n_in,
                              void* d_out, int out_size, void* d_ws, size_t ws_size,
                              hipStream_t stream) {
    const int*   char_ids = (const int*)d_in[0];
    const float* emb      = (const float*)d_in[1];
    const float* w_ih_f   = (const float*)d_in[2];
    const float* w_hh_f   = (const float*)d_in[3];
    const float* b_ih_f   = (const float*)d_in[4];
    const float* b_hh_f   = (const float*)d_in[5];
    const float* w_ih_r   = (const float*)d_in[6];
    const float* w_hh_r   = (const float*)d_in[7];
    const float* b_ih_r   = (const float*)d_in[8];
    const float* b_hh_r   = (const float*)d_in[9];
    float* out = (float*)d_out;
    float* tbl = (float*)d_ws; // [2][VOCAB][G4] = 160 KB

    const int nt = VOCAB * G4; // 20000
    build_tbl<<<(nt + 255) / 256, 256, 0, stream>>>(emb, w_ih_f, b_ih_f, b_hh_f, tbl);
    build_tbl<<<(nt + 255) / 256, 256, 0, stream>>>(emb, w_ih_r, b_ih_r, b_hh_r, tbl + nt);
    // 256 blocks: 128 per direction, 128 sequences (256 threads) per block.
    lstm_kernel<<<256, 256, 0, stream>>>(char_ids, tbl, w_hh_f, w_hh_r, out);
}

// Round 5
// 112.854 us; speedup vs baseline: 4.5495x; 4.2683x over previous
//
#include <hip/hip_runtime.h>

#define T 16
#define E 30
#define H 50
#define VOCAB 100
#define NSEQ 16384
#define RT 13           // M row-tiles of 16 -> 208 rows (200 real + 8 pad)
#define ROWS 208

typedef _Float16 v8hf __attribute__((ext_vector_type(8)));
typedef float v4f __attribute__((ext_vector_type(4)));

// tbl[dir][v][r] for interleaved gate-rows r = 4*unit + gate (gate order i,f,g,o)
// tbl[v][r] = dot(emb[v], w_ih[orig]) + b_ih[orig] + b_hh[orig], orig = gate*50+unit
__global__ void build_tbl(const float* __restrict__ emb,
                          const float* __restrict__ w_ih,
                          const float* __restrict__ b_ih,
                          const float* __restrict__ b_hh,
                          float* __restrict__ tbl) {
    int idx = blockIdx.x * blockDim.x + threadIdx.x;
    if (idx >= VOCAB * ROWS) return;
    int v = idx / ROWS, r = idx % ROWS;
    float s = 0.f;
    if (r < 4 * H) {
        int orig = (r & 3) * H + (r >> 2);
        s = b_ih[orig] + b_hh[orig];
        const float* er = emb + v * E;
        const float* wr = w_ih + orig * E;
#pragma unroll
        for (int e = 0; e < E; ++e) s += er[e] * wr[e];
    }
    tbl[idx] = s;
}

__device__ __forceinline__ float sigm(float x) { return 1.0f / (1.0f + __expf(-x)); }
__device__ __forceinline__ float ftanh(float x) {
    float e = __expf(2.0f * x);
    return (e - 1.0f) / (e + 1.0f);
}

// Wave owns 16 sequences of one direction. GEMM per step: gates^T = W(208x64) * h^T(64x16)
// via mfma_f32_16x16x32_f16. A-fragments (W, fp16) resident in VGPRs for the
// whole kernel. h round-trips a wave-private LDS buffer as fp16 hi+lo.
// Interleaved row order 4u+g makes gates lane-local in the C layout.
__global__ __launch_bounds__(256, 2) void lstm_mfma(
    const int* __restrict__ ids,     // [NSEQ, T]
    const float* __restrict__ tbl,   // [2][VOCAB][ROWS]
    const float* __restrict__ whh_f, // [200][50]
    const float* __restrict__ whh_r, // [200][50]
    float* __restrict__ out)         // [NSEQ, 100]
{
    // [wave][hi/lo][seq(16)][unit-slot(56)] fp16; slots 50..55 stay zero (K pad)
    __shared__ _Float16 hbuf[4][2][16][56];   // 14336 B

    const int tid = threadIdx.x;
    const int lane = tid & 63;
    const int wave = tid >> 6;
    const int l15 = lane & 15;      // seq within wave / col
    const int lg = lane >> 4;       // k-group / row-group
    const int b = blockIdx.x;
    const int dir = b >> 8;         // 0..255 fwd, 256..511 rev
    const int seq = (b & 255) * 64 + wave * 16 + l15;

    const float* __restrict__ whh = dir ? whh_r : whh_f;
    const float* __restrict__ tb  = tbl + dir * (VOCAB * ROWS);
    const int* __restrict__ myids = ids + seq * T;

    // zero this wave's h buffer (wave-private; program order suffices)
    {
        _Float16* hz = &hbuf[wave][0][0][0];
        for (int i = lane; i < 2 * 16 * 56; i += 64) hz[i] = (_Float16)0.f;
    }

    // ragged length -> capture step
    int capt;
    {
        const int4* q = (const int4*)myids;
        int4 a0 = q[0], a1 = q[1], a2 = q[2], a3 = q[3];
        int len = (a0.x != 0) + (a0.y != 0) + (a0.z != 0) + (a0.w != 0)
                + (a1.x != 0) + (a1.y != 0) + (a1.z != 0) + (a1.w != 0)
                + (a2.x != 0) + (a2.y != 0) + (a2.z != 0) + (a2.w != 0)
                + (a3.x != 0) + (a3.y != 0) + (a3.z != 0) + (a3.w != 0);
        capt = dir ? (T - 1) : ((len > 1) ? (len - 1) : 0);
    }

    // A-fragments: afrag[rt][kh], lane holds W[row=rt*16+l15][k=kh*32+lg*8+j]
    v8hf afrag[RT][2];
#pragma unroll
    for (int rt = 0; rt < RT; ++rt) {
        const int r = rt * 16 + l15;                 // interleaved row
        const int valid_r = (r < 4 * H);
        const int orig = valid_r ? ((r & 3) * H + (r >> 2)) : 0;
#pragma unroll
        for (int kh = 0; kh < 2; ++kh) {
            v8hf af;
#pragma unroll
            for (int j = 0; j < 8; ++j) {
                const int k = kh * 32 + lg * 8 + j;
                float wv = (valid_r && k < H) ? whh[orig * H + k] : 0.f;
                af[j] = (_Float16)wv;
            }
            afrag[rt][kh] = af;
        }
    }

    _Float16* hb_hi = &hbuf[wave][0][0][0];
    _Float16* hb_lo = &hbuf[wave][1][0][0];
    const int roff = l15 * 56 + lg * 8;      // consumer half-index (per kh add 32)
    const int woff = l15 * 56 + lg;          // producer half-index (per rt add rt*4)

    float cst[RT];
#pragma unroll
    for (int rt = 0; rt < RT; ++rt) cst[rt] = 0.f;

    int id_next = myids[dir ? (T - 1) : 0];

    for (int t = 0; t < T; ++t) {
        const int id = id_next;
        if (t < T - 1) id_next = myids[dir ? (T - 2 - t) : (t + 1)];
        const float* __restrict__ trow = tb + id * ROWS;

        // 1) issue tbl gathers (C init), all 13 in flight
        v4f tv[RT];
#pragma unroll
        for (int rt = 0; rt < RT; ++rt)
            tv[rt] = *(const v4f*)(trow + rt * 16 + lg * 4);

        // 2) B-fragments from LDS (prev step's h, or zeros at t=0)
        v8hf bh0 = *(const v8hf*)(hb_hi + roff);
        v8hf bh1 = *(const v8hf*)(hb_hi + roff + 32);
        v8hf bl0 = *(const v8hf*)(hb_lo + roff);
        v8hf bl1 = *(const v8hf*)(hb_lo + roff + 32);

        // 3) MFMA + lane-local LSTM elementwise per row-tile
#pragma unroll
        for (int rt = 0; rt < RT; ++rt) {
            v4f c = tv[rt];
            c = __builtin_amdgcn_mfma_f32_16x16x32_f16(afrag[rt][0], bh0, c, 0, 0, 0);
            c = __builtin_amdgcn_mfma_f32_16x16x32_f16(afrag[rt][1], bh1, c, 0, 0, 0);
            c = __builtin_amdgcn_mfma_f32_16x16x32_f16(afrag[rt][0], bl0, c, 0, 0, 0);
            c = __builtin_amdgcn_mfma_f32_16x16x32_f16(afrag[rt][1], bl1, c, 0, 0, 0);

            float i_ = sigm(c[0]);
            float f_ = sigm(c[1]);
            float g_ = ftanh(c[2]);
            float o_ = sigm(c[3]);
            float cn = fmaf(f_, cst[rt], i_ * g_);
            cst[rt] = cn;
            float hn = o_ * ftanh(cn);

            if (rt < 12 || lg < 2) {               // unit u = rt*4+lg < 50
                const int u = rt * 4 + lg;
                _Float16 hi = (_Float16)hn;
                _Float16 lo = (_Float16)(hn - (float)hi);
                hb_hi[woff + rt * 4] = hi;
                hb_lo[woff + rt * 4] = lo;
                if (t == capt) out[seq * 100 + dir * 50 + u] = hn;
            }
        }
    }
}

extern "C" void kernel_launch(void* const* d_in, const int* in_sizes, int n_in,
                              void* d_out, int out_size, void* d_ws, size_t ws_size,
                              hipStream_t stream) {
    const int*   char_ids = (const int*)d_in[0];
    const float* emb      = (const float*)d_in[1];
    const float* w_ih_f   = (const float*)d_in[2];
    const float* w_hh_f   = (const float*)d_in[3];
    const float* b_ih_f   = (const float*)d_in[4];
    const float* b_hh_f   = (const float*)d_in[5];
    const float* w_ih_r   = (const float*)d_in[6];
    const float* w_hh_r   = (const float*)d_in[7];
    const float* b_ih_r   = (const float*)d_in[8];
    const float* b_hh_r   = (const float*)d_in[9];
    float* out = (float*)d_out;
    float* tbl = (float*)d_ws; // [2][VOCAB][ROWS] f32 = 166.4 KB

    const int nt = VOCAB * ROWS; // 20800
    build_tbl<<<(nt + 255) / 256, 256, 0, stream>>>(emb, w_ih_f, b_ih_f, b_hh_f, tbl);
    build_tbl<<<(nt + 255) / 256, 256, 0, stream>>>(emb, w_ih_r, b_ih_r, b_hh_r, tbl + nt);
    // 512 blocks: 256 per direction, 64 seqs (4 independent waves x 16) per block
    lstm_mfma<<<512, 256, 0, stream>>>(char_ids, tbl, w_hh_f, w_hh_r, out);
}

// Round 6
// 77.200 us; speedup vs baseline: 6.6506x; 1.4618x over previous
//
#include <hip/hip_runtime.h>

#define T 16
#define E 30
#define H 50
#define VOCAB 100
#define NSEQ 16384
#define ROWS 208        // 13 row-tiles of 16; rows are interleaved r = 4*unit + gate

typedef _Float16 v8hf __attribute__((ext_vector_type(8)));
typedef float v4f __attribute__((ext_vector_type(4)));

// tbl[dir][v][r], r = 4*unit + gate (gate order i,f,g,o), orig row = gate*50+unit
__global__ void build_tbl(const float* __restrict__ emb,
                          const float* __restrict__ w_ih,
                          const float* __restrict__ b_ih,
                          const float* __restrict__ b_hh,
                          float* __restrict__ tbl) {
    int idx = blockIdx.x * blockDim.x + threadIdx.x;
    if (idx >= VOCAB * ROWS) return;
    int v = idx / ROWS, r = idx % ROWS;
    float s = 0.f;
    if (r < 4 * H) {
        int orig = (r & 3) * H + (r >> 2);
        s = b_ih[orig] + b_hh[orig];
        const float* er = emb + v * E;
        const float* wr = w_ih + orig * E;
#pragma unroll
        for (int e = 0; e < E; ++e) s += er[e] * wr[e];
    }
    tbl[idx] = s;
}

__device__ __forceinline__ float rcpf(float x) { return __builtin_amdgcn_rcpf(x); }
__device__ __forceinline__ float sigm(float x) { return rcpf(1.0f + __expf(-x)); }
__device__ __forceinline__ float ftanh(float x) {
    float e = __expf(2.0f * x);
    return (e - 1.0f) * rcpf(e + 1.0f);
}

// hbuf layout (fp16): [buf][grp][hi/lo][seq16][slot56]
#define HL_STRIDE  (16 * 56)            // 896 halves
#define BUF_STRIDE (2 * 2 * 16 * 56)    // per-buffer stride in halves (2 grps x 2 hl)
#define GRP_STRIDE (2 * 16 * 56)        // 1792 halves

// One wave processes row-tiles [RT0, RT0+NT) for its 16-sequence group.
template<int RT0, int NT>
__device__ __forceinline__ void run_half(
    const float* __restrict__ whh, const float* __restrict__ tb,
    const int* __restrict__ myids, _Float16* __restrict__ hb0,
    float* __restrict__ out, int seq, int dir, int capt, int l15, int lg)
{
    // A-fragments resident for the whole kernel: afrag[i][kh][j] =
    // W[r = (RT0+i)*16 + l15][k = kh*32 + lg*8 + j], fp16, zero-padded.
    v8hf afrag[NT][2];
#pragma unroll
    for (int i = 0; i < NT; ++i) {
        const int r = (RT0 + i) * 16 + l15;
        const bool vr = (r < 4 * H);
        const int orig = vr ? ((r & 3) * H + (r >> 2)) : 0;
#pragma unroll
        for (int kh = 0; kh < 2; ++kh) {
            v8hf af;
#pragma unroll
            for (int j = 0; j < 8; ++j) {
                const int k = kh * 32 + lg * 8 + j;
                af[j] = (_Float16)((vr && k < H) ? whh[orig * H + k] : 0.f);
            }
            afrag[i][kh] = af;
        }
    }
    float cst[NT];
#pragma unroll
    for (int i = 0; i < NT; ++i) cst[i] = 0.f;

    const int roff = l15 * 56 + lg * 8;        // B-frag read offset (halves)
    const int woff = l15 * 56 + RT0 * 4 + lg;  // h write offset (halves)

    int id_next = myids[dir ? (T - 1) : 0];

    for (int t = 0; t < T; ++t) {
        const int cur = t & 1, nxt = cur ^ 1;
        const int id = id_next;
        if (t < T - 1) id_next = myids[dir ? (T - 2 - t) : (t + 1)];
        const float* __restrict__ trow = tb + id * ROWS;

        // B-fragments: previous step's h (hi + lo halves), double-buffered
        const _Float16* rb = hb0 + cur * BUF_STRIDE;
        v8hf bh0 = *(const v8hf*)(rb + roff);
        v8hf bh1 = *(const v8hf*)(rb + roff + 32);
        v8hf bl0 = *(const v8hf*)(rb + HL_STRIDE + roff);
        v8hf bl1 = *(const v8hf*)(rb + HL_STRIDE + roff + 32);

        _Float16* wb = hb0 + nxt * BUF_STRIDE + woff;

#pragma unroll
        for (int i = 0; i < NT; ++i) {
            const int rt = RT0 + i;
            // C init straight from the id-table gather (compiler hoists loads)
            v4f c = *(const v4f*)(trow + rt * 16 + lg * 4);
            c = __builtin_amdgcn_mfma_f32_16x16x32_f16(afrag[i][0], bh0, c, 0, 0, 0);
            c = __builtin_amdgcn_mfma_f32_16x16x32_f16(afrag[i][1], bh1, c, 0, 0, 0);
            c = __builtin_amdgcn_mfma_f32_16x16x32_f16(afrag[i][0], bl0, c, 0, 0, 0);
            c = __builtin_amdgcn_mfma_f32_16x16x32_f16(afrag[i][1], bl1, c, 0, 0, 0);

            float i_ = sigm(c[0]);
            float f_ = sigm(c[1]);
            float g_ = ftanh(c[2]);
            float o_ = sigm(c[3]);
            float cn = fmaf(f_, cst[i], i_ * g_);
            cst[i] = cn;
            float hn = o_ * ftanh(cn);

            const int u = rt * 4 + lg;
            if (u < H) {                        // runtime only for the pad tile
                _Float16 hi = (_Float16)hn;
                wb[i * 4] = hi;
                wb[HL_STRIDE + i * 4] = (_Float16)(hn - (float)hi);
                if (t == capt) out[seq * 100 + dir * H + u] = hn;
            }
        }
        __syncthreads();   // h(t) writes visible before step t+1 reads
    }
}

__global__ __launch_bounds__(256, 4) void lstm_mfma(
    const int* __restrict__ ids,     // [NSEQ, T]
    const float* __restrict__ tbl,   // [2][VOCAB][ROWS]
    const float* __restrict__ whh_f, // [200][50]
    const float* __restrict__ whh_r, // [200][50]
    float* __restrict__ out)         // [NSEQ, 100]
{
    __shared__ _Float16 hbuf[2][2][2][16][56];   // 14336 B

    const int tid = threadIdx.x;
    const int lane = tid & 63;
    const int wave = tid >> 6;
    const int grp = wave >> 1;       // sequence group within block (2 per block)
    const int half = wave & 1;       // row-half: 0 -> rt 0..6, 1 -> rt 7..12
    const int l15 = lane & 15;       // seq within group / C col
    const int lg = lane >> 4;        // k-/row-group
    const int b = blockIdx.x;
    const int dir = b >> 9;          // 1024 blocks: 0..511 fwd, 512..1023 rev
    const int seq = (b & 511) * 32 + grp * 16 + l15;

    const float* __restrict__ whh = dir ? whh_r : whh_f;
    const float* __restrict__ tb  = tbl + dir * (VOCAB * ROWS);
    const int* __restrict__ myids = ids + seq * T;

    // zero both h double-buffers (incl. K-pad slots 50..55)
    {
        int* hz = (int*)&hbuf[0][0][0][0][0];
#pragma unroll
        for (int i = tid; i < (int)(sizeof(hbuf) / 4); i += 256) hz[i] = 0;
    }

    // ragged length -> capture step (per lane's own sequence)
    int capt;
    {
        const int4* q = (const int4*)myids;
        int4 a0 = q[0], a1 = q[1], a2 = q[2], a3 = q[3];
        int len = (a0.x != 0) + (a0.y != 0) + (a0.z != 0) + (a0.w != 0)
                + (a1.x != 0) + (a1.y != 0) + (a1.z != 0) + (a1.w != 0)
                + (a2.x != 0) + (a2.y != 0) + (a2.z != 0) + (a2.w != 0)
                + (a3.x != 0) + (a3.y != 0) + (a3.z != 0) + (a3.w != 0);
        capt = dir ? (T - 1) : ((len > 1) ? (len - 1) : 0);
    }

    __syncthreads();   // hbuf zeroed

    _Float16* hb0 = &hbuf[0][grp][0][0][0];
    if (half == 0)
        run_half<0, 7>(whh, tb, myids, hb0, out, seq, dir, capt, l15, lg);
    else
        run_half<7, 6>(whh, tb, myids, hb0, out, seq, dir, capt, l15, lg);
}

extern "C" void kernel_launch(void* const* d_in, const int* in_sizes, int n_in,
                              void* d_out, int out_size, void* d_ws, size_t ws_size,
                              hipStream_t stream) {
    const int*   char_ids = (const int*)d_in[0];
    const float* emb      = (const float*)d_in[1];
    const float* w_ih_f   = (const float*)d_in[2];
    const float* w_hh_f   = (const float*)d_in[3];
    const float* b_ih_f   = (const float*)d_in[4];
    const float* b_hh_f   = (const float*)d_in[5];
    const float* w_ih_r   = (const float*)d_in[6];
    const float* w_hh_r   = (const float*)d_in[7];
    const float* b_ih_r   = (const float*)d_in[8];
    const float* b_hh_r   = (const float*)d_in[9];
    float* out = (float*)d_out;
    float* tbl = (float*)d_ws; // [2][VOCAB][ROWS] f32 = 166.4 KB

    const int nt = VOCAB * ROWS; // 20800
    build_tbl<<<(nt + 255) / 256, 256, 0, stream>>>(emb, w_ih_f, b_ih_f, b_hh_f, tbl);
    build_tbl<<<(nt + 255) / 256, 256, 0, stream>>>(emb, w_ih_r, b_ih_r, b_hh_r, tbl + nt);
    // 1024 blocks: 512 per direction; block = 2 seq-groups x 2 row-half waves
    lstm_mfma<<<1024, 256, 0, stream>>>(char_ids, tbl, w_hh_f, w_hh_r, out);
}